// Round 3
// baseline (206.138 us; speedup 1.0000x reference)
//
#include <hip/hip_runtime.h>
#include <hip/hip_bf16.h>
#include <math.h>

#define BB 32
#define NN 4096
#define DD 512
#define HH 128
#define LN_EPS 1e-5f
#define MEPS 1e-8f

typedef __attribute__((ext_vector_type(8))) short bf16x8;
typedef __attribute__((ext_vector_type(4))) float f32x4;

__device__ __forceinline__ unsigned pk_bf16(float a, float b) {
    unsigned ua = __float_as_uint(a); ua = (ua + 0x7FFFu + ((ua >> 16) & 1u)) >> 16;
    unsigned ub = __float_as_uint(b); ub = (ub + 0x7FFFu + ((ub >> 16) & 1u)) >> 16;
    return ua | (ub << 16);
}
__device__ __forceinline__ unsigned short bf16_1(float a) {
    unsigned ua = __float_as_uint(a);
    return (unsigned short)((ua + 0x7FFFu + ((ua >> 16) & 1u)) >> 16);
}
__device__ __forceinline__ float bflo(unsigned u) { return __uint_as_float(u << 16); }
__device__ __forceinline__ float bfhi(unsigned u) { return __uint_as_float(u & 0xFFFF0000u); }

// ---- prep: mask sniff+expand (blocks 0..511) + w1->bf16 transpose (512..767)
__global__ __launch_bounds__(256) void gmsp_prep(
    const void* __restrict__ mask, unsigned char* __restrict__ m8,
    const float* __restrict__ w1, unsigned short* __restrict__ w1t)
{
    int blk = blockIdx.x, t = threadIdx.x;
    if (blk < 512) {
        __shared__ int sf[2];
        const unsigned* mu = (const unsigned*)mask;
        bool f32f = false, i8f = false;
#pragma unroll
        for (int i = 0; i < 4; ++i) {
            unsigned v = mu[t + i * 256];
            f32f |= (v == 0x3F800000u);
            i8f  |= (v > 1u) && (v != 0x3F800000u);
        }
        if (t == 0) { sf[0] = 0; sf[1] = 0; }
        __syncthreads();
        int wf32 = __any((int)f32f), wi8 = __any((int)i8f);
        if ((t & 63) == 0) {
            if (wf32) atomicOr(&sf[0], 1);
            if (wi8)  atomicOr(&sf[1], 1);
        }
        __syncthreads();
        int fmt = sf[0] ? 2 : (sf[1] ? 1 : 0);
        int i = blk * 256 + t;
        unsigned char v;
        if (fmt == 1)      v = ((const unsigned char*)mask)[i] != 0;
        else if (fmt == 2) v = ((const float*)mask)[i] != 0.0f;
        else               v = ((const int*)mask)[i] != 0;
        m8[i] = v;
    } else {
        int idx = (blk - 512) * 256 + t;   // 65536 = 512k x 128h
        int k = idx >> 7, h = idx & 127;
        w1t[h * DD + k] = bf16_1(w1[idx]);
    }
}

// ---- fused persistent: pipelined stage + scores MFMA + flash softmax + pools
__global__ __launch_bounds__(512, 2) void gmsp_fused(
    const float* __restrict__ x, const unsigned short* __restrict__ w1t,
    const float* __restrict__ b1, const float* __restrict__ w2,
    const float* __restrict__ b2, const unsigned char* __restrict__ m8,
    float* __restrict__ attnp, float* __restrict__ sump, float* __restrict__ maxp,
    float* __restrict__ bm, float* __restrict__ bt, float* __restrict__ bc)
{
    __shared__ char xs[64 * 1024];          // one 64x512 bf16 tile, XOR-swizzled
    __shared__ float sred[8][64];
    __shared__ float wrow[64];
    __shared__ unsigned char mrow_s[64];
    __shared__ float sM, sT, sCnt, sScale;

    int t = threadIdx.x;
    int lane = t & 63, wid = t >> 6;
    int l15 = lane & 15, lq = lane >> 4;
    int blk = blockIdx.x;
    int b = blk >> 3, q = blk & 7;
    size_t row0 = (size_t)b * NN + (size_t)q * 512;

    // register-resident B fragments: wave wid owns h-cols [wid*16, wid*16+16)
    int hb = wid * 16;
    bf16x8 breg[16];
    {
        const unsigned short* wp = w1t + (size_t)(hb + l15) * DD + lq * 8;
#pragma unroll
        for (int s = 0; s < 16; ++s) breg[s] = *(const bf16x8*)(wp + s * 32);
    }
    float b1v = b1[hb + l15], w2v = w2[hb + l15];
    float b2v = b2[0];

    if (t == 0) { sM = -INFINITY; sT = 0.f; sCnt = 0.f; }

    // pool accumulators: lane owns cols [lane*8, lane*8+8)
    float a_acc[8], s_acc[8], m_acc[8];
#pragma unroll
    for (int j = 0; j < 8; ++j) { a_acc[j] = 0.f; s_acc[j] = 0.f; m_acc[j] = -INFINITY; }

    float4 sreg[16];
    unsigned char mreg[8];
    {   // issue tile 0 (wave wid loads rows {it*8+wid}, lane cols [lane*8,+8))
        const float* xb = x + (row0 + wid) * DD + lane * 8;
#pragma unroll
        for (int it = 0; it < 8; ++it) {
            const float4* src = (const float4*)(xb + (size_t)it * 8 * DD);
            sreg[2 * it] = src[0];
            sreg[2 * it + 1] = src[1];
            mreg[it] = m8[row0 + it * 8 + wid];
        }
    }

    for (int t8 = 0; t8 < 8; ++t8) {
        // ---- convert staged regs -> bf16 LDS; accumulate sum/max from fp32 --
#pragma unroll
        for (int it = 0; it < 8; ++it) {
            int row = it * 8 + wid;
            float4 v0 = sreg[2 * it], v1 = sreg[2 * it + 1];
            uint4 w;
            w.x = pk_bf16(v0.x, v0.y); w.y = pk_bf16(v0.z, v0.w);
            w.z = pk_bf16(v1.x, v1.y); w.w = pk_bf16(v1.z, v1.w);
            *(uint4*)(xs + row * 1024 + ((lane * 16) ^ ((row & 7) << 4))) = w;
            if (lane == 0) mrow_s[row] = mreg[it];
            if (mreg[it]) {                     // wave-uniform branch
                s_acc[0] += v0.x; s_acc[1] += v0.y; s_acc[2] += v0.z; s_acc[3] += v0.w;
                s_acc[4] += v1.x; s_acc[5] += v1.y; s_acc[6] += v1.z; s_acc[7] += v1.w;
                m_acc[0] = fmaxf(m_acc[0], v0.x); m_acc[1] = fmaxf(m_acc[1], v0.y);
                m_acc[2] = fmaxf(m_acc[2], v0.z); m_acc[3] = fmaxf(m_acc[3], v0.w);
                m_acc[4] = fmaxf(m_acc[4], v1.x); m_acc[5] = fmaxf(m_acc[5], v1.y);
                m_acc[6] = fmaxf(m_acc[6], v1.z); m_acc[7] = fmaxf(m_acc[7], v1.w);
            }
        }
        // ---- issue next tile's loads (in flight across the compute phase) --
        if (t8 < 7) {
            const float* xb = x + (row0 + (t8 + 1) * 64 + wid) * DD + lane * 8;
#pragma unroll
            for (int it = 0; it < 8; ++it) {
                const float4* src = (const float4*)(xb + (size_t)it * 8 * DD);
                sreg[2 * it] = src[0];
                sreg[2 * it + 1] = src[1];
                mreg[it] = m8[row0 + (t8 + 1) * 64 + it * 8 + wid];
            }
        }
        __syncthreads();

        // ---- MFMA: 64 rows x 16 h per wave --------------------------------
        f32x4 acc[4];
#pragma unroll
        for (int mt = 0; mt < 4; ++mt) acc[mt] = (f32x4)0.f;
#pragma unroll
        for (int s = 0; s < 16; ++s) {
            int kb = s * 64 + lq * 16;
#pragma unroll
            for (int mt = 0; mt < 4; ++mt) {
                int row = mt * 16 + l15;
                bf16x8 af = *(const bf16x8*)(xs + row * 1024 + (kb ^ ((row & 7) << 4)));
                acc[mt] = __builtin_amdgcn_mfma_f32_16x16x32_bf16(af, breg[s], acc[mt], 0, 0, 0);
            }
        }
        // tanh + w2 dot; reduce over the 16 h-lanes (l15)
#pragma unroll
        for (int mt = 0; mt < 4; ++mt) {
#pragma unroll
            for (int r = 0; r < 4; ++r) {
                float pv = acc[mt][r] + b1v;
                pv = fminf(fmaxf(pv, -10.f), 10.f);
                float e2 = __expf(2.f * pv);
                float v = (e2 - 1.f) / (e2 + 1.f) * w2v;
                v += __shfl_xor(v, 1); v += __shfl_xor(v, 2);
                v += __shfl_xor(v, 4); v += __shfl_xor(v, 8);
                if (l15 == 0) sred[wid][mt * 16 + lq * 4 + r] = v;
            }
        }
        __syncthreads();

        // ---- flash softmax update (wave 0) --------------------------------
        if (t < 64) {
            float sc = sred[0][t] + sred[1][t] + sred[2][t] + sred[3][t]
                     + sred[4][t] + sred[5][t] + sred[6][t] + sred[7][t] + b2v;
            bool valid = mrow_s[t] != 0;
            float score = valid ? sc : -INFINITY;
            float mx = score;
            mx = fmaxf(mx, __shfl_xor(mx, 1));  mx = fmaxf(mx, __shfl_xor(mx, 2));
            mx = fmaxf(mx, __shfl_xor(mx, 4));  mx = fmaxf(mx, __shfl_xor(mx, 8));
            mx = fmaxf(mx, __shfl_xor(mx, 16)); mx = fmaxf(mx, __shfl_xor(mx, 32));
            float Mold = sM;
            float Mnew, scale;
            if (mx == -INFINITY) { Mnew = Mold; scale = 1.f; }
            else { Mnew = fmaxf(Mold, mx); scale = __expf(Mold - Mnew); }
            float wv = valid ? __expf(score - Mnew) : 0.f;
            wrow[t] = wv;
            float ts = wv, tc = valid ? 1.f : 0.f;
            ts += __shfl_xor(ts, 1);  tc += __shfl_xor(tc, 1);
            ts += __shfl_xor(ts, 2);  tc += __shfl_xor(tc, 2);
            ts += __shfl_xor(ts, 4);  tc += __shfl_xor(tc, 4);
            ts += __shfl_xor(ts, 8);  tc += __shfl_xor(tc, 8);
            ts += __shfl_xor(ts, 16); tc += __shfl_xor(tc, 16);
            ts += __shfl_xor(ts, 32); tc += __shfl_xor(tc, 32);
            if (t == 0) { sT = sT * scale + ts; sCnt += tc; sM = Mnew; sScale = scale; }
        }
        __syncthreads();

        // ---- attn replay with flash rescale -------------------------------
        float scl = sScale;
#pragma unroll
        for (int j = 0; j < 8; ++j) a_acc[j] *= scl;
#pragma unroll
        for (int it = 0; it < 8; ++it) {
            int row = it * 8 + wid;
            float wv = wrow[row];
            uint4 xv = *(const uint4*)(xs + row * 1024 + ((lane * 16) ^ ((row & 7) << 4)));
            a_acc[0] = fmaf(wv, bflo(xv.x), a_acc[0]);
            a_acc[1] = fmaf(wv, bfhi(xv.x), a_acc[1]);
            a_acc[2] = fmaf(wv, bflo(xv.y), a_acc[2]);
            a_acc[3] = fmaf(wv, bfhi(xv.y), a_acc[3]);
            a_acc[4] = fmaf(wv, bflo(xv.z), a_acc[4]);
            a_acc[5] = fmaf(wv, bfhi(xv.z), a_acc[5]);
            a_acc[6] = fmaf(wv, bflo(xv.w), a_acc[6]);
            a_acc[7] = fmaf(wv, bfhi(xv.w), a_acc[7]);
        }
        __syncthreads();
    }

    // ---- epilogue: cross-wave reduce via LDS (reuse tile buffer) ----------
    float* red = (float*)xs;
    int colb = lane * 8;
#pragma unroll
    for (int j = 0; j < 8; ++j) {
        red[wid * 512 + colb + j]        = a_acc[j];
        red[4096 + wid * 512 + colb + j] = s_acc[j];
        red[8192 + wid * 512 + colb + j] = m_acc[j];
    }
    __syncthreads();
    float av = 0.f, sv = 0.f, mv = -INFINITY;
#pragma unroll
    for (int w = 0; w < 8; ++w) {
        av += red[w * 512 + t];
        sv += red[4096 + w * 512 + t];
        mv = fmaxf(mv, red[8192 + w * 512 + t]);
    }
    attnp[(size_t)blk * DD + t] = av;
    sump[(size_t)blk * DD + t]  = sv;
    maxp[(size_t)blk * DD + t]  = mv;
    if (t == 0) { bm[blk] = sM; bt[blk] = sT; bc[blk] = sCnt; }
}

// ---- tail: flash-combine 8 sub-blocks + gate MLP + out proj ---------------
__device__ __forceinline__ float gmsp_block_sum(float v, float* red, int t) {
    __syncthreads();
    red[t] = v; __syncthreads();
    for (int s = 128; s > 0; s >>= 1) { if (t < s) red[t] += red[t + s]; __syncthreads(); }
    return red[0];
}

__global__ __launch_bounds__(256) void gmsp_tail(
    const float* __restrict__ attnp, const float* __restrict__ sump,
    const float* __restrict__ maxp, const float* __restrict__ bm,
    const float* __restrict__ bt, const float* __restrict__ bc,
    const float* __restrict__ gate_w1, const float* __restrict__ gate_b1,
    const float* __restrict__ gln_g, const float* __restrict__ gln_b,
    const float* __restrict__ gate_w2, const float* __restrict__ gate_b2,
    const float* __restrict__ out_w, const float* __restrict__ out_b,
    const float* __restrict__ oln_g, const float* __restrict__ oln_b,
    float* __restrict__ out)
{
    __shared__ float comb[3 * DD];
    __shared__ float wvec[DD];
    __shared__ float red[256];
    int b = blockIdx.x, t = threadIdx.x;

    float m_sb[8], e_sb[8];
    float M = -INFINITY;
#pragma unroll
    for (int sb = 0; sb < 8; ++sb) { m_sb[sb] = bm[b * 8 + sb]; M = fmaxf(M, m_sb[sb]); }
    float T = 0.f, cnt = 0.f;
#pragma unroll
    for (int sb = 0; sb < 8; ++sb) {
        float e = (m_sb[sb] == -INFINITY) ? 0.f : __expf(m_sb[sb] - M);
        e_sb[sb] = e;
        T += e * bt[b * 8 + sb];
        cnt += bc[b * 8 + sb];
    }
    float invT = T > 0.f ? 1.f / T : 0.f;
    cnt = fmaxf(cnt, MEPS);

    int d0 = t * 2;
    float ax = 0.f, ay = 0.f, sx = 0.f, sy = 0.f, mx = -INFINITY, my = -INFINITY;
#pragma unroll
    for (int sb = 0; sb < 8; ++sb) {
        size_t base = (size_t)(b * 8 + sb) * DD + d0;
        float2 av = *(const float2*)(attnp + base);
        float2 svv = *(const float2*)(sump + base);
        float2 xvv = *(const float2*)(maxp + base);
        ax = fmaf(e_sb[sb], av.x, ax); ay = fmaf(e_sb[sb], av.y, ay);
        sx += svv.x; sy += svv.y;
        mx = fmaxf(mx, xvv.x); my = fmaxf(my, xvv.y);
    }
    ax *= invT; ay *= invT;
    float icnt = 1.f / cnt;
    float meanx = sx * icnt, meany = sy * icnt;
    if (isinf(mx)) mx = 0.f;
    if (isinf(my)) my = 0.f;

    comb[d0] = ax;               comb[d0 + 1] = ay;
    comb[DD + d0] = mx;          comb[DD + d0 + 1] = my;
    comb[2 * DD + d0] = meanx;   comb[2 * DD + d0 + 1] = meany;
    __syncthreads();

    float2 g = {gate_b1[d0], gate_b1[d0 + 1]};
    for (int k = 0; k < 3 * DD; ++k) {
        float c = comb[k];
        float2 wv = *(const float2*)(gate_w1 + (size_t)k * DD + d0);
        g.x = fmaf(c, wv.x, g.x); g.y = fmaf(c, wv.y, g.y);
    }
    float mg = gmsp_block_sum(g.x + g.y, red, t) * (1.f / DD);
    float vg = gmsp_block_sum(g.x * g.x + g.y * g.y, red, t) * (1.f / DD) - mg * mg;
    float inv = rsqrtf(vg + LN_EPS);
    float gx = (g.x - mg) * inv * gln_g[d0] + gln_b[d0];
    float gy = (g.y - mg) * inv * gln_g[d0 + 1] + gln_b[d0 + 1];
    gx = 0.5f * gx * (1.f + erff(gx * 0.70710678118654752f));
    gy = 0.5f * gy * (1.f + erff(gy * 0.70710678118654752f));

    float p0 = gx * gate_w2[d0 * 3 + 0] + gy * gate_w2[(d0 + 1) * 3 + 0];
    float p1 = gx * gate_w2[d0 * 3 + 1] + gy * gate_w2[(d0 + 1) * 3 + 1];
    float p2 = gx * gate_w2[d0 * 3 + 2] + gy * gate_w2[(d0 + 1) * 3 + 2];
    float l0 = gmsp_block_sum(p0, red, t) + gate_b2[0];
    float l1 = gmsp_block_sum(p1, red, t) + gate_b2[1];
    float l2 = gmsp_block_sum(p2, red, t) + gate_b2[2];
    float mxl = fmaxf(l0, fmaxf(l1, l2));
    float e0 = __expf(l0 - mxl), e1 = __expf(l1 - mxl), e2 = __expf(l2 - mxl);
    float ie = 1.f / (e0 + e1 + e2);
    float gw0 = e0 * ie, gw1 = e1 * ie, gw2 = e2 * ie;

    wvec[d0]     = ax * gw0 + mx * gw1 + meanx * gw2;
    wvec[d0 + 1] = ay * gw0 + my * gw1 + meany * gw2;
    __syncthreads();

    float2 o = {out_b[d0], out_b[d0 + 1]};
    for (int d = 0; d < DD; ++d) {
        float wd = wvec[d];
        float2 ow = *(const float2*)(out_w + (size_t)d * DD + d0);
        o.x = fmaf(wd, ow.x, o.x); o.y = fmaf(wd, ow.y, o.y);
    }
    float mo = gmsp_block_sum(o.x + o.y, red, t) * (1.f / DD);
    float vo = gmsp_block_sum(o.x * o.x + o.y * o.y, red, t) * (1.f / DD) - mo * mo;
    float io = rsqrtf(vo + LN_EPS);
    float2 res;
    res.x = (o.x - mo) * io * oln_g[d0] + oln_b[d0];
    res.y = (o.y - mo) * io * oln_g[d0 + 1] + oln_b[d0 + 1];
    *(float2*)(out + (size_t)b * DD + d0) = res;
}

extern "C" void kernel_launch(void* const* d_in, const int* in_sizes, int n_in,
                              void* d_out, int out_size, void* d_ws, size_t ws_size,
                              hipStream_t stream) {
    const float* x        = (const float*)d_in[0];
    const void*  mask     = d_in[1];
    const float* attn_w1  = (const float*)d_in[2];
    const float* attn_b1  = (const float*)d_in[3];
    const float* attn_w2  = (const float*)d_in[4];
    const float* attn_b2  = (const float*)d_in[5];
    const float* gate_w1  = (const float*)d_in[6];
    const float* gate_b1  = (const float*)d_in[7];
    const float* gln_g    = (const float*)d_in[8];
    const float* gln_b    = (const float*)d_in[9];
    const float* gate_w2  = (const float*)d_in[10];
    const float* gate_b2  = (const float*)d_in[11];
    const float* out_w    = (const float*)d_in[12];
    const float* out_b    = (const float*)d_in[13];
    const float* oln_g    = (const float*)d_in[14];
    const float* oln_b    = (const float*)d_in[15];
    float* out = (float*)d_out;

    char* p = (char*)d_ws;
    unsigned char* m8 = (unsigned char*)p;      p += (size_t)BB * NN;          // 128 KB
    unsigned short* w1t = (unsigned short*)p;   p += (size_t)DD * HH * 2;      // 128 KB
    float* attnp = (float*)p;                   p += (size_t)256 * DD * 4;     // 512 KB
    float* sump = (float*)p;                    p += (size_t)256 * DD * 4;
    float* maxp = (float*)p;                    p += (size_t)256 * DD * 4;
    float* bm = (float*)p;                      p += 1024;
    float* bt = (float*)p;                      p += 1024;
    float* bc = (float*)p;                      p += 1024;

    gmsp_prep<<<768, 256, 0, stream>>>(mask, m8, attn_w1, w1t);
    gmsp_fused<<<256, 512, 0, stream>>>(x, w1t, attn_b1, attn_w2, attn_b2, m8,
                                        attnp, sump, maxp, bm, bt, bc);
    gmsp_tail<<<BB, 256, 0, stream>>>(attnp, sump, maxp, bm, bt, bc,
                                      gate_w1, gate_b1, gln_g, gln_b, gate_w2, gate_b2,
                                      out_w, out_b, oln_g, oln_b, out);
}

// Round 4
// 179.778 us; speedup vs baseline: 1.1466x; 1.1466x over previous
//
#include <hip/hip_runtime.h>
#include <hip/hip_bf16.h>
#include <math.h>

#define BB 32
#define NN 4096
#define DD 512
#define HH 128
#define LN_EPS 1e-5f
#define MEPS 1e-8f

typedef __attribute__((ext_vector_type(8))) short bf16x8;
typedef __attribute__((ext_vector_type(4))) float f32x4;

__device__ __forceinline__ unsigned pk_bf16(float a, float b) {
    unsigned ua = __float_as_uint(a); ua = (ua + 0x7FFFu + ((ua >> 16) & 1u)) >> 16;
    unsigned ub = __float_as_uint(b); ub = (ub + 0x7FFFu + ((ub >> 16) & 1u)) >> 16;
    return ua | (ub << 16);
}
__device__ __forceinline__ unsigned short bf16_1(float a) {
    unsigned ua = __float_as_uint(a);
    return (unsigned short)((ua + 0x7FFFu + ((ua >> 16) & 1u)) >> 16);
}

// ---- prep: mask sniff+expand (blocks 0..511) + w1->bf16 transpose (512..767)
__global__ __launch_bounds__(256) void gmsp_prep(
    const void* __restrict__ mask, unsigned char* __restrict__ m8,
    const float* __restrict__ w1, unsigned short* __restrict__ w1t)
{
    int blk = blockIdx.x, t = threadIdx.x;
    if (blk < 512) {
        __shared__ int sf[2];
        const unsigned* mu = (const unsigned*)mask;
        bool f32f = false, i8f = false;
#pragma unroll
        for (int i = 0; i < 4; ++i) {
            unsigned v = mu[t + i * 256];
            f32f |= (v == 0x3F800000u);
            i8f  |= (v > 1u) && (v != 0x3F800000u);
        }
        if (t == 0) { sf[0] = 0; sf[1] = 0; }
        __syncthreads();
        int wf32 = __any((int)f32f), wi8 = __any((int)i8f);
        if ((t & 63) == 0) {
            if (wf32) atomicOr(&sf[0], 1);
            if (wi8)  atomicOr(&sf[1], 1);
        }
        __syncthreads();
        int fmt = sf[0] ? 2 : (sf[1] ? 1 : 0);
        int i = blk * 256 + t;
        unsigned char v;
        if (fmt == 1)      v = ((const unsigned char*)mask)[i] != 0;
        else if (fmt == 2) v = ((const float*)mask)[i] != 0.0f;
        else               v = ((const int*)mask)[i] != 0;
        m8[i] = v;
    } else {
        int idx = (blk - 512) * 256 + t;   // 65536 = 512k x 128h
        int k = idx >> 7, h = idx & 127;
        w1t[h * DD + k] = bf16_1(w1[idx]);
    }
}

// ---- fused: pipelined (raw-barrier) stage + scores MFMA + flash softmax + pools
__global__ __launch_bounds__(512, 1) void gmsp_fused(
    const float* __restrict__ x, const unsigned short* __restrict__ w1t,
    const float* __restrict__ b1, const float* __restrict__ w2,
    const float* __restrict__ b2, const unsigned char* __restrict__ m8,
    float* __restrict__ attnp, float* __restrict__ sump, float* __restrict__ maxp,
    float* __restrict__ bm, float* __restrict__ bt, float* __restrict__ bc)
{
    __shared__ char xs[49152];        // [0,32K): bf16 tile 32x1024B swizzled; epilogue reuses all 48K
    __shared__ float sred[32][8];

    const int t = threadIdx.x;
    const int lane = t & 63, wid = t >> 6;
    const int l15 = lane & 15, lq = lane >> 4;
    const int blk = blockIdx.x;
    const int b = blk >> 3, q = blk & 7;
    const size_t grow0 = (size_t)b * NN + (size_t)q * 512;

    float4 regA[8], regB[8];
    int mA = 0, mB = 0;

    // issue tile 0 loads first so x starts flowing
    {
        const float* xb = x + (grow0 + wid * 4) * (size_t)DD;
#pragma unroll
        for (int rr = 0; rr < 4; ++rr) {
            regA[rr * 2 + 0] = *(const float4*)(xb + (size_t)rr * DD + lane * 4);
            regA[rr * 2 + 1] = *(const float4*)(xb + (size_t)rr * DD + 256 + lane * 4);
        }
        mA = m8[grow0 + (lane & 31)];
    }

    // register-resident B fragments: wave wid owns h-cols [wid*16, wid*16+16)
    bf16x8 breg[16];
    {
        const unsigned short* wp = w1t + (size_t)(wid * 16 + l15) * DD + lq * 8;
#pragma unroll
        for (int s = 0; s < 16; ++s) breg[s] = *(const bf16x8*)(wp + s * 32);
    }
    const float b1v = b1[wid * 16 + l15];
    const float w2v = w2[wid * 16 + l15];
    const float b2v = b2[0];

    float a_acc[8], s_acc[8], m_acc[8];
#pragma unroll
    for (int j = 0; j < 8; ++j) { a_acc[j] = 0.f; s_acc[j] = 0.f; m_acc[j] = -INFINITY; }
    float Mw = -INFINITY, Tw = 0.f, Cw = 0.f;

    auto tile_body = [&](int tt, float4 (&cur)[8], int mc, float4 (&nxt)[8], int& mn,
                         bool dopref) {
        // ---- A: convert cur -> LDS bf16 (swizzled); sum/max pool from fp32 ----
#pragma unroll
        for (int rr = 0; rr < 4; ++rr) {
            const int row = wid * 4 + rr;
            const int swz = (row & 7) << 4;
            const int mrv = __shfl(mc, row);
#pragma unroll
            for (int jj = 0; jj < 2; ++jj) {
                float4 v = cur[rr * 2 + jj];
                uint2 pw; pw.x = pk_bf16(v.x, v.y); pw.y = pk_bf16(v.z, v.w);
                *(uint2*)(xs + row * 1024 + ((jj * 512 + lane * 8) ^ swz)) = pw;
                if (mrv) {   // wave-uniform (broadcast)
                    s_acc[jj * 4 + 0] += v.x; s_acc[jj * 4 + 1] += v.y;
                    s_acc[jj * 4 + 2] += v.z; s_acc[jj * 4 + 3] += v.w;
                    m_acc[jj * 4 + 0] = fmaxf(m_acc[jj * 4 + 0], v.x);
                    m_acc[jj * 4 + 1] = fmaxf(m_acc[jj * 4 + 1], v.y);
                    m_acc[jj * 4 + 2] = fmaxf(m_acc[jj * 4 + 2], v.z);
                    m_acc[jj * 4 + 3] = fmaxf(m_acc[jj * 4 + 3], v.w);
                }
            }
        }
        // ---- issue next tile's loads (stay in flight across raw barriers) ----
        if (dopref) {
            const float* xb = x + (grow0 + (size_t)(tt + 1) * 32 + wid * 4) * (size_t)DD;
#pragma unroll
            for (int rr = 0; rr < 4; ++rr) {
                nxt[rr * 2 + 0] = *(const float4*)(xb + (size_t)rr * DD + lane * 4);
                nxt[rr * 2 + 1] = *(const float4*)(xb + (size_t)rr * DD + 256 + lane * 4);
            }
            mn = m8[grow0 + (size_t)(tt + 1) * 32 + (lane & 31)];
        }
        asm volatile("s_waitcnt lgkmcnt(0)" ::: "memory");
        __builtin_amdgcn_s_barrier();          // raw: does NOT drain vmcnt

        // ---- B: MFMA 32 rows x 16 h (per wave), K=512 ----
        f32x4 acc0 = (f32x4)0.f, acc1 = (f32x4)0.f;
#pragma unroll
        for (int s = 0; s < 16; ++s) {
            const int r0 = l15, r1 = 16 + l15;
            bf16x8 a0 = *(const bf16x8*)(xs + r0 * 1024 + (((s * 4 + lq) ^ (r0 & 7)) << 4));
            bf16x8 a1 = *(const bf16x8*)(xs + r1 * 1024 + (((s * 4 + lq) ^ (r1 & 7)) << 4));
            acc0 = __builtin_amdgcn_mfma_f32_16x16x32_bf16(a0, breg[s], acc0, 0, 0, 0);
            acc1 = __builtin_amdgcn_mfma_f32_16x16x32_bf16(a1, breg[s], acc1, 0, 0, 0);
        }
        // tanh + w2 dot; reduce over the 16 h-lanes
#pragma unroll
        for (int mt = 0; mt < 2; ++mt) {
            f32x4 ac = mt ? acc1 : acc0;
#pragma unroll
            for (int r = 0; r < 4; ++r) {
                float pv = ac[r] + b1v;
                pv = fminf(fmaxf(pv, -10.f), 10.f);
                float e2 = __expf(2.f * pv);
                float v = (e2 - 1.f) / (e2 + 1.f) * w2v;
                v += __shfl_xor(v, 1); v += __shfl_xor(v, 2);
                v += __shfl_xor(v, 4); v += __shfl_xor(v, 8);
                if (l15 == 0) sred[mt * 16 + lq * 4 + r][wid] = v;
            }
        }
        asm volatile("s_waitcnt lgkmcnt(0)" ::: "memory");
        __builtin_amdgcn_s_barrier();

        // ---- C: flash softmax, redundantly in every wave (identical state) ----
        {
            const int rl = lane & 31;
            float4 s0 = *(const float4*)&sred[rl][0];
            float4 s1 = *(const float4*)&sred[rl][4];
            float ssc = s0.x + s0.y + s0.z + s0.w + s1.x + s1.y + s1.z + s1.w + b2v;
            bool val = (lane < 32) && (mc != 0);
            float score = val ? ssc : -INFINITY;
            float mx = score;
            mx = fmaxf(mx, __shfl_xor(mx, 1));  mx = fmaxf(mx, __shfl_xor(mx, 2));
            mx = fmaxf(mx, __shfl_xor(mx, 4));  mx = fmaxf(mx, __shfl_xor(mx, 8));
            mx = fmaxf(mx, __shfl_xor(mx, 16)); mx = fmaxf(mx, __shfl_xor(mx, 32));
            float Mnew = fmaxf(Mw, mx);
            float scale = (Mw == -INFINITY) ? ((Mnew == -INFINITY) ? 1.f : 0.f)
                                            : __expf(Mw - Mnew);
            float wv = val ? __expf(score - Mnew) : 0.f;
            float ts = wv, tc = val ? 1.f : 0.f;
            ts += __shfl_xor(ts, 1);  tc += __shfl_xor(tc, 1);
            ts += __shfl_xor(ts, 2);  tc += __shfl_xor(tc, 2);
            ts += __shfl_xor(ts, 4);  tc += __shfl_xor(tc, 4);
            ts += __shfl_xor(ts, 8);  tc += __shfl_xor(tc, 8);
            ts += __shfl_xor(ts, 16); tc += __shfl_xor(tc, 16);
            ts += __shfl_xor(ts, 32); tc += __shfl_xor(tc, 32);
            Tw = Tw * scale + ts; Cw += tc; Mw = Mnew;
#pragma unroll
            for (int j = 0; j < 8; ++j) a_acc[j] *= scale;

            // ---- D: attention replay from the fp32 staging registers ----
#pragma unroll
            for (int rr = 0; rr < 4; ++rr) {
                float w4 = __shfl(wv, wid * 4 + rr);
#pragma unroll
                for (int jj = 0; jj < 2; ++jj) {
                    float4 v = cur[rr * 2 + jj];
                    a_acc[jj * 4 + 0] = fmaf(w4, v.x, a_acc[jj * 4 + 0]);
                    a_acc[jj * 4 + 1] = fmaf(w4, v.y, a_acc[jj * 4 + 1]);
                    a_acc[jj * 4 + 2] = fmaf(w4, v.z, a_acc[jj * 4 + 2]);
                    a_acc[jj * 4 + 3] = fmaf(w4, v.w, a_acc[jj * 4 + 3]);
                }
            }
        }
    };

    for (int p = 0; p < 8; ++p) {
        tile_body(2 * p,     regA, mA, regB, mB, true);
        tile_body(2 * p + 1, regB, mB, regA, mA, p < 7);
    }

    // ---- epilogue: cross-wave reduce via LDS ----
    asm volatile("s_waitcnt lgkmcnt(0)" ::: "memory");
    __builtin_amdgcn_s_barrier();
    float* red = (float*)xs;   // a:[0,4096) s:[4096,8192) m:[8192,12288) floats
#pragma unroll
    for (int jj = 0; jj < 2; ++jj) {
        int col = jj * 256 + lane * 4;
        *(float4*)&red[wid * 512 + col]        = make_float4(a_acc[jj*4+0], a_acc[jj*4+1], a_acc[jj*4+2], a_acc[jj*4+3]);
        *(float4*)&red[4096 + wid * 512 + col] = make_float4(s_acc[jj*4+0], s_acc[jj*4+1], s_acc[jj*4+2], s_acc[jj*4+3]);
        *(float4*)&red[8192 + wid * 512 + col] = make_float4(m_acc[jj*4+0], m_acc[jj*4+1], m_acc[jj*4+2], m_acc[jj*4+3]);
    }
    asm volatile("s_waitcnt lgkmcnt(0)" ::: "memory");
    __builtin_amdgcn_s_barrier();
    float av = 0.f, sv = 0.f, mv = -INFINITY;
#pragma unroll
    for (int w = 0; w < 8; ++w) {
        av += red[w * 512 + t];
        sv += red[4096 + w * 512 + t];
        mv = fmaxf(mv, red[8192 + w * 512 + t]);
    }
    attnp[(size_t)blk * DD + t] = av;
    sump[(size_t)blk * DD + t]  = sv;
    maxp[(size_t)blk * DD + t]  = mv;
    if (t == 0) { bm[blk] = Mw; bt[blk] = Tw; bc[blk] = Cw; }
}

// ---- tail: flash-combine 8 sub-blocks + gate MLP + out proj ---------------
__device__ __forceinline__ float gmsp_block_sum(float v, float* red, int t) {
    __syncthreads();
    red[t] = v; __syncthreads();
    for (int s = 128; s > 0; s >>= 1) { if (t < s) red[t] += red[t + s]; __syncthreads(); }
    return red[0];
}

__global__ __launch_bounds__(256) void gmsp_tail(
    const float* __restrict__ attnp, const float* __restrict__ sump,
    const float* __restrict__ maxp, const float* __restrict__ bm,
    const float* __restrict__ bt, const float* __restrict__ bc,
    const float* __restrict__ gate_w1, const float* __restrict__ gate_b1,
    const float* __restrict__ gln_g, const float* __restrict__ gln_b,
    const float* __restrict__ gate_w2, const float* __restrict__ gate_b2,
    const float* __restrict__ out_w, const float* __restrict__ out_b,
    const float* __restrict__ oln_g, const float* __restrict__ oln_b,
    float* __restrict__ out)
{
    __shared__ float comb[3 * DD];
    __shared__ float wvec[DD];
    __shared__ float red[256];
    int b = blockIdx.x, t = threadIdx.x;

    float m_sb[8], e_sb[8];
    float M = -INFINITY;
#pragma unroll
    for (int sb = 0; sb < 8; ++sb) { m_sb[sb] = bm[b * 8 + sb]; M = fmaxf(M, m_sb[sb]); }
    float T = 0.f, cnt = 0.f;
#pragma unroll
    for (int sb = 0; sb < 8; ++sb) {
        float e = (m_sb[sb] == -INFINITY) ? 0.f : __expf(m_sb[sb] - M);
        e_sb[sb] = e;
        T += e * bt[b * 8 + sb];
        cnt += bc[b * 8 + sb];
    }
    float invT = T > 0.f ? 1.f / T : 0.f;
    cnt = fmaxf(cnt, MEPS);

    int d0 = t * 2;
    float ax = 0.f, ay = 0.f, sx = 0.f, sy = 0.f, mx = -INFINITY, my = -INFINITY;
#pragma unroll
    for (int sb = 0; sb < 8; ++sb) {
        size_t base = (size_t)(b * 8 + sb) * DD + d0;
        float2 av = *(const float2*)(attnp + base);
        float2 svv = *(const float2*)(sump + base);
        float2 xvv = *(const float2*)(maxp + base);
        ax = fmaf(e_sb[sb], av.x, ax); ay = fmaf(e_sb[sb], av.y, ay);
        sx += svv.x; sy += svv.y;
        mx = fmaxf(mx, xvv.x); my = fmaxf(my, xvv.y);
    }
    ax *= invT; ay *= invT;
    float icnt = 1.f / cnt;
    float meanx = sx * icnt, meany = sy * icnt;
    if (isinf(mx)) mx = 0.f;
    if (isinf(my)) my = 0.f;

    comb[d0] = ax;               comb[d0 + 1] = ay;
    comb[DD + d0] = mx;          comb[DD + d0 + 1] = my;
    comb[2 * DD + d0] = meanx;   comb[2 * DD + d0 + 1] = meany;
    __syncthreads();

    float2 g = {gate_b1[d0], gate_b1[d0 + 1]};
    for (int k = 0; k < 3 * DD; ++k) {
        float c = comb[k];
        float2 wv = *(const float2*)(gate_w1 + (size_t)k * DD + d0);
        g.x = fmaf(c, wv.x, g.x); g.y = fmaf(c, wv.y, g.y);
    }
    float mg = gmsp_block_sum(g.x + g.y, red, t) * (1.f / DD);
    float vg = gmsp_block_sum(g.x * g.x + g.y * g.y, red, t) * (1.f / DD) - mg * mg;
    float inv = rsqrtf(vg + LN_EPS);
    float gx = (g.x - mg) * inv * gln_g[d0] + gln_b[d0];
    float gy = (g.y - mg) * inv * gln_g[d0 + 1] + gln_b[d0 + 1];
    gx = 0.5f * gx * (1.f + erff(gx * 0.70710678118654752f));
    gy = 0.5f * gy * (1.f + erff(gy * 0.70710678118654752f));

    float p0 = gx * gate_w2[d0 * 3 + 0] + gy * gate_w2[(d0 + 1) * 3 + 0];
    float p1 = gx * gate_w2[d0 * 3 + 1] + gy * gate_w2[(d0 + 1) * 3 + 1];
    float p2 = gx * gate_w2[d0 * 3 + 2] + gy * gate_w2[(d0 + 1) * 3 + 2];
    float l0 = gmsp_block_sum(p0, red, t) + gate_b2[0];
    float l1 = gmsp_block_sum(p1, red, t) + gate_b2[1];
    float l2 = gmsp_block_sum(p2, red, t) + gate_b2[2];
    float mxl = fmaxf(l0, fmaxf(l1, l2));
    float e0 = __expf(l0 - mxl), e1 = __expf(l1 - mxl), e2 = __expf(l2 - mxl);
    float ie = 1.f / (e0 + e1 + e2);
    float gw0 = e0 * ie, gw1 = e1 * ie, gw2 = e2 * ie;

    wvec[d0]     = ax * gw0 + mx * gw1 + meanx * gw2;
    wvec[d0 + 1] = ay * gw0 + my * gw1 + meany * gw2;
    __syncthreads();

    float2 o = {out_b[d0], out_b[d0 + 1]};
    for (int d = 0; d < DD; ++d) {
        float wd = wvec[d];
        float2 ow = *(const float2*)(out_w + (size_t)d * DD + d0);
        o.x = fmaf(wd, ow.x, o.x); o.y = fmaf(wd, ow.y, o.y);
    }
    float mo = gmsp_block_sum(o.x + o.y, red, t) * (1.f / DD);
    float vo = gmsp_block_sum(o.x * o.x + o.y * o.y, red, t) * (1.f / DD) - mo * mo;
    float io = rsqrtf(vo + LN_EPS);
    float2 res;
    res.x = (o.x - mo) * io * oln_g[d0] + oln_b[d0];
    res.y = (o.y - mo) * io * oln_g[d0 + 1] + oln_b[d0 + 1];
    *(float2*)(out + (size_t)b * DD + d0) = res;
}

extern "C" void kernel_launch(void* const* d_in, const int* in_sizes, int n_in,
                              void* d_out, int out_size, void* d_ws, size_t ws_size,
                              hipStream_t stream) {
    const float* x        = (const float*)d_in[0];
    const void*  mask     = d_in[1];
    const float* attn_w1  = (const float*)d_in[2];
    const float* attn_b1  = (const float*)d_in[3];
    const float* attn_w2  = (const float*)d_in[4];
    const float* attn_b2  = (const float*)d_in[5];
    const float* gate_w1  = (const float*)d_in[6];
    const float* gate_b1  = (const float*)d_in[7];
    const float* gln_g    = (const float*)d_in[8];
    const float* gln_b    = (const float*)d_in[9];
    const float* gate_w2  = (const float*)d_in[10];
    const float* gate_b2  = (const float*)d_in[11];
    const float* out_w    = (const float*)d_in[12];
    const float* out_b    = (const float*)d_in[13];
    const float* oln_g    = (const float*)d_in[14];
    const float* oln_b    = (const float*)d_in[15];
    float* out = (float*)d_out;

    char* p = (char*)d_ws;
    unsigned char* m8 = (unsigned char*)p;      p += (size_t)BB * NN;          // 128 KB
    unsigned short* w1t = (unsigned short*)p;   p += (size_t)DD * HH * 2;      // 128 KB
    float* attnp = (float*)p;                   p += (size_t)256 * DD * 4;     // 512 KB
    float* sump = (float*)p;                    p += (size_t)256 * DD * 4;
    float* maxp = (float*)p;                    p += (size_t)256 * DD * 4;
    float* bm = (float*)p;                      p += 1024;
    float* bt = (float*)p;                      p += 1024;
    float* bc = (float*)p;                      p += 1024;

    gmsp_prep<<<768, 256, 0, stream>>>(mask, m8, attn_w1, w1t);
    gmsp_fused<<<256, 512, 0, stream>>>(x, w1t, attn_b1, attn_w2, attn_b2, m8,
                                        attnp, sump, maxp, bm, bt, bc);
    gmsp_tail<<<BB, 256, 0, stream>>>(attnp, sump, maxp, bm, bt, bc,
                                      gate_w1, gate_b1, gln_g, gln_b, gate_w2, gate_b2,
                                      out_w, out_b, oln_g, oln_b, out);
}

// Round 5
// 166.999 us; speedup vs baseline: 1.2344x; 1.0765x over previous
//
#include <hip/hip_runtime.h>
#include <hip/hip_bf16.h>
#include <math.h>

#define BB 32
#define NN 4096
#define DD 512
#define HH 128
#define NT 32          // 16-row tiles per block (512 rows/block)
#define TR 16          // rows per tile
#define LN_EPS 1e-5f
#define MEPS 1e-8f

typedef __attribute__((ext_vector_type(8))) short bf16x8;
typedef __attribute__((ext_vector_type(4))) float f32x4;

__device__ __forceinline__ unsigned pk_bf16(float a, float b) {
    unsigned ua = __float_as_uint(a); ua = (ua + 0x7FFFu + ((ua >> 16) & 1u)) >> 16;
    unsigned ub = __float_as_uint(b); ub = (ub + 0x7FFFu + ((ub >> 16) & 1u)) >> 16;
    return ua | (ub << 16);
}
__device__ __forceinline__ unsigned short bf16_1(float a) {
    unsigned ua = __float_as_uint(a);
    return (unsigned short)((ua + 0x7FFFu + ((ua >> 16) & 1u)) >> 16);
}
__device__ __forceinline__ float bflo(unsigned u) { return __uint_as_float(u << 16); }
__device__ __forceinline__ float bfhi(unsigned u) { return __uint_as_float(u & 0xFFFF0000u); }

__device__ __forceinline__ void dma16(const void* g, void* l) {
    __builtin_amdgcn_global_load_lds((const __attribute__((address_space(1))) void*)g,
                                     (__attribute__((address_space(3))) void*)l, 16, 0, 0);
}

// ---- prep: mask sniff+expand (blocks 0..511) + w1->bf16 transpose (512..767)
__global__ __launch_bounds__(256) void gmsp_prep(
    const void* __restrict__ mask, unsigned char* __restrict__ m8,
    const float* __restrict__ w1, unsigned short* __restrict__ w1t)
{
    int blk = blockIdx.x, t = threadIdx.x;
    if (blk < 512) {
        __shared__ int sf[2];
        const unsigned* mu = (const unsigned*)mask;
        bool f32f = false, i8f = false;
#pragma unroll
        for (int i = 0; i < 4; ++i) {
            unsigned v = mu[t + i * 256];
            f32f |= (v == 0x3F800000u);
            i8f  |= (v > 1u) && (v != 0x3F800000u);
        }
        if (t == 0) { sf[0] = 0; sf[1] = 0; }
        __syncthreads();
        int wf32 = __any((int)f32f), wi8 = __any((int)i8f);
        if ((t & 63) == 0) {
            if (wf32) atomicOr(&sf[0], 1);
            if (wi8)  atomicOr(&sf[1], 1);
        }
        __syncthreads();
        int fmt = sf[0] ? 2 : (sf[1] ? 1 : 0);
        int i = blk * 256 + t;
        unsigned char v;
        if (fmt == 1)      v = ((const unsigned char*)mask)[i] != 0;
        else if (fmt == 2) v = ((const float*)mask)[i] != 0.0f;
        else               v = ((const int*)mask)[i] != 0;
        m8[i] = v;
    } else {
        int idx = (blk - 512) * 256 + t;   // 65536 = 512k x 128h
        int k = idx >> 7, h = idx & 127;
        w1t[h * DD + k] = bf16_1(w1[idx]);
    }
}

// ---- fused: DMA-pipelined (counted vmcnt) scores MFMA + flash softmax + pools
__global__ __launch_bounds__(512, 1) void gmsp_fused(
    const float* __restrict__ x, const unsigned short* __restrict__ w1t,
    const float* __restrict__ b1, const float* __restrict__ w2,
    const float* __restrict__ b2, const unsigned char* __restrict__ m8,
    float* __restrict__ attnp, float* __restrict__ sump, float* __restrict__ maxp,
    float* __restrict__ bm, float* __restrict__ bt, float* __restrict__ bc)
{
    __shared__ float Fb[2][TR][DD];            // 64 KB fp32 DMA staging (linear)
    __shared__ unsigned short Btile[TR * DD];  // 16 KB bf16 MFMA tile (XOR-swizzled)
    __shared__ float sred[TR][8];

    const int t = threadIdx.x;
    const int lane = t & 63, wid = t >> 6;
    const int l15 = lane & 15, lq = lane >> 4;
    const int blk = blockIdx.x;
    const size_t grow0 = (size_t)(blk >> 3) * NN + (size_t)(blk & 7) * 512;

    // mask bytes for this block's 512 rows: lane holds rows [8*lane, 8*lane+8)
    const uint2 mu = *(const uint2*)(m8 + grow0 + 8 * lane);

    // W1 B-fragments register-resident: wave owns h-cols [wid*16, wid*16+16)
    bf16x8 breg[16];
    {
        const unsigned short* wp = w1t + (size_t)(wid * 16 + l15) * DD + lq * 8;
#pragma unroll
        for (int s = 0; s < 16; ++s) breg[s] = *(const bf16x8*)(wp + s * 32);
    }
    const float b1v = b1[wid * 16 + l15];
    const float w2v = w2[wid * 16 + l15];
    const float b2v = b2[0];

    float a_acc[8], s_acc[8], m_acc[8];
#pragma unroll
    for (int j = 0; j < 8; ++j) { a_acc[j] = 0.f; s_acc[j] = 0.f; m_acc[j] = -INFINITY; }
    float Mw = -INFINITY, Tw = 0.f, Cw = 0.f;

    // stage tile tt into Fb[buf]: wave wid DMAs chunks 4w..4w+3 == its own rows 2w,2w+1
    auto stage = [&](int tt, int buf) {
#pragma unroll
        for (int i = 0; i < 4; ++i) {
            const int c = wid * 4 + i;
            const int row = c >> 1, half = c & 1;
            const float* g = x + (grow0 + (size_t)tt * TR + row) * DD + half * 256 + lane * 4;
            dma16(g, (void*)&Fb[buf][row][half * 256]);
        }
    };

    stage(0, 0);
    stage(1, 1);

    for (int tt = 0; tt < NT; ++tt) {
        const int cur = tt & 1;
        // ---- A: own DMA chunks for tile tt landed (stage tt+1 stays in flight)
        if (tt < NT - 1) { asm volatile("s_waitcnt vmcnt(4)" ::: "memory"); }
        else             { asm volatile("s_waitcnt vmcnt(0)" ::: "memory"); }
        __builtin_amdgcn_sched_barrier(0);

        // ---- B: convert own 2 rows fp32->bf16 (swizzled) + fp32 sum/max pool
#pragma unroll
        for (int rr = 0; rr < 2; ++rr) {
            const int row = wid * 2 + rr;
            float4 v0 = *(const float4*)&Fb[cur][row][4 * lane];
            float4 v1 = *(const float4*)&Fb[cur][row][256 + 4 * lane];
            uint2 p0, p1;
            p0.x = pk_bf16(v0.x, v0.y); p0.y = pk_bf16(v0.z, v0.w);
            p1.x = pk_bf16(v1.x, v1.y); p1.y = pk_bf16(v1.z, v1.w);
            const int swz = (row & 7) << 4;
            char* bb = (char*)Btile + row * 1024;
            *(uint2*)(bb + ((8 * lane) ^ swz)) = p0;
            *(uint2*)(bb + ((512 + 8 * lane) ^ swz)) = p1;
            const int idx = tt * TR + row;            // wave-uniform
            unsigned lo = __shfl((int)mu.x, idx >> 3);
            unsigned hi = __shfl((int)mu.y, idx >> 3);
            unsigned ws = (idx & 4) ? hi : lo;
            if ((ws >> ((idx & 3) * 8)) & 0xFF) {
                s_acc[0] += v0.x; s_acc[1] += v0.y; s_acc[2] += v0.z; s_acc[3] += v0.w;
                s_acc[4] += v1.x; s_acc[5] += v1.y; s_acc[6] += v1.z; s_acc[7] += v1.w;
                m_acc[0] = fmaxf(m_acc[0], v0.x); m_acc[1] = fmaxf(m_acc[1], v0.y);
                m_acc[2] = fmaxf(m_acc[2], v0.z); m_acc[3] = fmaxf(m_acc[3], v0.w);
                m_acc[4] = fmaxf(m_acc[4], v1.x); m_acc[5] = fmaxf(m_acc[5], v1.y);
                m_acc[6] = fmaxf(m_acc[6], v1.z); m_acc[7] = fmaxf(m_acc[7], v1.w);
            }
        }
        asm volatile("s_waitcnt lgkmcnt(0)" ::: "memory");
        __builtin_amdgcn_s_barrier();              // #1: Fb[cur] read done, Btile written

        // ---- C: issue stage(tt+2) into the buffer just freed (fire-and-forget)
        if (tt < NT - 2) stage(tt + 2, cur);

        // ---- D: MFMA 16 rows x 16 h per wave (A from Btile, B reg-resident)
        f32x4 acc = (f32x4)0.f;
        {
            const char* bbase = (const char*)Btile + l15 * 1024;
            const int swzr = (l15 & 7) << 4;
#pragma unroll
            for (int s = 0; s < 16; ++s) {
                bf16x8 af = *(const bf16x8*)(bbase + ((s * 64 + lq * 16) ^ swzr));
                acc = __builtin_amdgcn_mfma_f32_16x16x32_bf16(af, breg[s], acc, 0, 0, 0);
            }
        }
#pragma unroll
        for (int r = 0; r < 4; ++r) {
            float pv = acc[r] + b1v;
            pv = fminf(fmaxf(pv, -10.f), 10.f);
            float e2 = __expf(2.f * pv);
            float v = (e2 - 1.f) / (e2 + 1.f) * w2v;
            v += __shfl_xor(v, 1); v += __shfl_xor(v, 2);
            v += __shfl_xor(v, 4); v += __shfl_xor(v, 8);
            if (l15 == 0) sred[lq * 4 + r][wid] = v;
        }
        asm volatile("s_waitcnt lgkmcnt(0)" ::: "memory");
        __builtin_amdgcn_s_barrier();              // #2: sred visible, Btile reads done

        // ---- E: flash softmax update, redundant (identical) in every wave
        float4 sr0 = *(const float4*)&sred[l15][0];
        float4 sr1 = *(const float4*)&sred[l15][4];
        float ssc = sr0.x + sr0.y + sr0.z + sr0.w
                  + sr1.x + sr1.y + sr1.z + sr1.w + b2v;
        const int eidx = tt * TR + l15;
        unsigned elo = __shfl((int)mu.x, eidx >> 3);
        unsigned ehi = __shfl((int)mu.y, eidx >> 3);
        unsigned ew = (eidx & 4) ? ehi : elo;
        bool val = ((ew >> ((eidx & 3) * 8)) & 0xFF) != 0;
        float score = val ? ssc : -INFINITY;
        float mx = score;
        mx = fmaxf(mx, __shfl_xor(mx, 1)); mx = fmaxf(mx, __shfl_xor(mx, 2));
        mx = fmaxf(mx, __shfl_xor(mx, 4)); mx = fmaxf(mx, __shfl_xor(mx, 8));
        float Mnew = fmaxf(Mw, mx);
        float scale = (Mw == -INFINITY) ? ((Mnew == -INFINITY) ? 1.f : 0.f)
                                        : __expf(Mw - Mnew);
        float wv = val ? __expf(score - Mnew) : 0.f;
        float ts = wv, tc = val ? 1.f : 0.f;
        ts += __shfl_xor(ts, 1); tc += __shfl_xor(tc, 1);
        ts += __shfl_xor(ts, 2); tc += __shfl_xor(tc, 2);
        ts += __shfl_xor(ts, 4); tc += __shfl_xor(tc, 4);
        ts += __shfl_xor(ts, 8); tc += __shfl_xor(tc, 8);
        Tw = Tw * scale + ts; Cw += tc; Mw = Mnew;
#pragma unroll
        for (int j = 0; j < 8; ++j) a_acc[j] *= scale;

        // ---- F: attn replay of own 2 rows from bf16 tile
        float wr0 = __shfl(wv, wid * 2);
        float wr1 = __shfl(wv, wid * 2 + 1);
#pragma unroll
        for (int rr = 0; rr < 2; ++rr) {
            const int row = wid * 2 + rr;
            const float wr = rr ? wr1 : wr0;
            const char* bb = (const char*)Btile + row * 1024;
            const int swz = (row & 7) << 4;
            uint2 u0 = *(const uint2*)(bb + ((8 * lane) ^ swz));
            uint2 u1 = *(const uint2*)(bb + ((512 + 8 * lane) ^ swz));
            a_acc[0] = fmaf(wr, bflo(u0.x), a_acc[0]);
            a_acc[1] = fmaf(wr, bfhi(u0.x), a_acc[1]);
            a_acc[2] = fmaf(wr, bflo(u0.y), a_acc[2]);
            a_acc[3] = fmaf(wr, bfhi(u0.y), a_acc[3]);
            a_acc[4] = fmaf(wr, bflo(u1.x), a_acc[4]);
            a_acc[5] = fmaf(wr, bfhi(u1.x), a_acc[5]);
            a_acc[6] = fmaf(wr, bflo(u1.y), a_acc[6]);
            a_acc[7] = fmaf(wr, bfhi(u1.y), a_acc[7]);
        }
    }

    // ---- epilogue: cross-wave reduce (reuse Fb as 3x [8][512] fp32) ----
    asm volatile("s_waitcnt lgkmcnt(0)" ::: "memory");
    __builtin_amdgcn_s_barrier();
    float* red = (float*)Fb;
    {
        const int c0 = 4 * lane, c1 = 256 + 4 * lane;
        *(float4*)&red[wid * 512 + c0]        = make_float4(a_acc[0], a_acc[1], a_acc[2], a_acc[3]);
        *(float4*)&red[wid * 512 + c1]        = make_float4(a_acc[4], a_acc[5], a_acc[6], a_acc[7]);
        *(float4*)&red[4096 + wid * 512 + c0] = make_float4(s_acc[0], s_acc[1], s_acc[2], s_acc[3]);
        *(float4*)&red[4096 + wid * 512 + c1] = make_float4(s_acc[4], s_acc[5], s_acc[6], s_acc[7]);
        *(float4*)&red[8192 + wid * 512 + c0] = make_float4(m_acc[0], m_acc[1], m_acc[2], m_acc[3]);
        *(float4*)&red[8192 + wid * 512 + c1] = make_float4(m_acc[4], m_acc[5], m_acc[6], m_acc[7]);
    }
    asm volatile("s_waitcnt lgkmcnt(0)" ::: "memory");
    __builtin_amdgcn_s_barrier();
    float av = 0.f, sv = 0.f, mv = -INFINITY;
#pragma unroll
    for (int w = 0; w < 8; ++w) {
        av += red[w * 512 + t];
        sv += red[4096 + w * 512 + t];
        mv = fmaxf(mv, red[8192 + w * 512 + t]);
    }
    attnp[(size_t)blk * DD + t] = av;
    sump[(size_t)blk * DD + t]  = sv;
    maxp[(size_t)blk * DD + t]  = mv;
    if (t == 0) { bm[blk] = Mw; bt[blk] = Tw; bc[blk] = Cw; }
}

// ---- tail: flash-combine 8 sub-blocks + gate MLP + out proj ---------------
__device__ __forceinline__ float gmsp_block_sum(float v, float* red, int t) {
    __syncthreads();
    red[t] = v; __syncthreads();
    for (int s = 128; s > 0; s >>= 1) { if (t < s) red[t] += red[t + s]; __syncthreads(); }
    return red[0];
}

__global__ __launch_bounds__(256) void gmsp_tail(
    const float* __restrict__ attnp, const float* __restrict__ sump,
    const float* __restrict__ maxp, const float* __restrict__ bm,
    const float* __restrict__ bt, const float* __restrict__ bc,
    const float* __restrict__ gate_w1, const float* __restrict__ gate_b1,
    const float* __restrict__ gln_g, const float* __restrict__ gln_b,
    const float* __restrict__ gate_w2, const float* __restrict__ gate_b2,
    const float* __restrict__ out_w, const float* __restrict__ out_b,
    const float* __restrict__ oln_g, const float* __restrict__ oln_b,
    float* __restrict__ out)
{
    __shared__ float comb[3 * DD];
    __shared__ float wvec[DD];
    __shared__ float red[256];
    int b = blockIdx.x, t = threadIdx.x;

    float m_sb[8], e_sb[8];
    float M = -INFINITY;
#pragma unroll
    for (int sb = 0; sb < 8; ++sb) { m_sb[sb] = bm[b * 8 + sb]; M = fmaxf(M, m_sb[sb]); }
    float T = 0.f, cnt = 0.f;
#pragma unroll
    for (int sb = 0; sb < 8; ++sb) {
        float e = (m_sb[sb] == -INFINITY) ? 0.f : __expf(m_sb[sb] - M);
        e_sb[sb] = e;
        T += e * bt[b * 8 + sb];
        cnt += bc[b * 8 + sb];
    }
    float invT = T > 0.f ? 1.f / T : 0.f;
    cnt = fmaxf(cnt, MEPS);

    int d0 = t * 2;
    float ax = 0.f, ay = 0.f, sx = 0.f, sy = 0.f, mx = -INFINITY, my = -INFINITY;
#pragma unroll
    for (int sb = 0; sb < 8; ++sb) {
        size_t base = (size_t)(b * 8 + sb) * DD + d0;
        float2 av = *(const float2*)(attnp + base);
        float2 svv = *(const float2*)(sump + base);
        float2 xvv = *(const float2*)(maxp + base);
        ax = fmaf(e_sb[sb], av.x, ax); ay = fmaf(e_sb[sb], av.y, ay);
        sx += svv.x; sy += svv.y;
        mx = fmaxf(mx, xvv.x); my = fmaxf(my, xvv.y);
    }
    ax *= invT; ay *= invT;
    float icnt = 1.f / cnt;
    float meanx = sx * icnt, meany = sy * icnt;
    if (isinf(mx)) mx = 0.f;
    if (isinf(my)) my = 0.f;

    comb[d0] = ax;               comb[d0 + 1] = ay;
    comb[DD + d0] = mx;          comb[DD + d0 + 1] = my;
    comb[2 * DD + d0] = meanx;   comb[2 * DD + d0 + 1] = meany;
    __syncthreads();

    float2 g = {gate_b1[d0], gate_b1[d0 + 1]};
    for (int k = 0; k < 3 * DD; ++k) {
        float c = comb[k];
        float2 wv = *(const float2*)(gate_w1 + (size_t)k * DD + d0);
        g.x = fmaf(c, wv.x, g.x); g.y = fmaf(c, wv.y, g.y);
    }
    float mg = gmsp_block_sum(g.x + g.y, red, t) * (1.f / DD);
    float vg = gmsp_block_sum(g.x * g.x + g.y * g.y, red, t) * (1.f / DD) - mg * mg;
    float inv = rsqrtf(vg + LN_EPS);
    float gx = (g.x - mg) * inv * gln_g[d0] + gln_b[d0];
    float gy = (g.y - mg) * inv * gln_g[d0 + 1] + gln_b[d0 + 1];
    gx = 0.5f * gx * (1.f + erff(gx * 0.70710678118654752f));
    gy = 0.5f * gy * (1.f + erff(gy * 0.70710678118654752f));

    float p0 = gx * gate_w2[d0 * 3 + 0] + gy * gate_w2[(d0 + 1) * 3 + 0];
    float p1 = gx * gate_w2[d0 * 3 + 1] + gy * gate_w2[(d0 + 1) * 3 + 1];
    float p2 = gx * gate_w2[d0 * 3 + 2] + gy * gate_w2[(d0 + 1) * 3 + 2];
    float l0 = gmsp_block_sum(p0, red, t) + gate_b2[0];
    float l1 = gmsp_block_sum(p1, red, t) + gate_b2[1];
    float l2 = gmsp_block_sum(p2, red, t) + gate_b2[2];
    float mxl = fmaxf(l0, fmaxf(l1, l2));
    float e0 = __expf(l0 - mxl), e1 = __expf(l1 - mxl), e2 = __expf(l2 - mxl);
    float ie = 1.f / (e0 + e1 + e2);
    float gw0 = e0 * ie, gw1 = e1 * ie, gw2 = e2 * ie;

    wvec[d0]     = ax * gw0 + mx * gw1 + meanx * gw2;
    wvec[d0 + 1] = ay * gw0 + my * gw1 + meany * gw2;
    __syncthreads();

    float2 o = {out_b[d0], out_b[d0 + 1]};
    for (int d = 0; d < DD; ++d) {
        float wd = wvec[d];
        float2 ow = *(const float2*)(out_w + (size_t)d * DD + d0);
        o.x = fmaf(wd, ow.x, o.x); o.y = fmaf(wd, ow.y, o.y);
    }
    float mo = gmsp_block_sum(o.x + o.y, red, t) * (1.f / DD);
    float vo = gmsp_block_sum(o.x * o.x + o.y * o.y, red, t) * (1.f / DD) - mo * mo;
    float io = rsqrtf(vo + LN_EPS);
    float2 res;
    res.x = (o.x - mo) * io * oln_g[d0] + oln_b[d0];
    res.y = (o.y - mo) * io * oln_g[d0 + 1] + oln_b[d0 + 1];
    *(float2*)(out + (size_t)b * DD + d0) = res;
}

extern "C" void kernel_launch(void* const* d_in, const int* in_sizes, int n_in,
                              void* d_out, int out_size, void* d_ws, size_t ws_size,
                              hipStream_t stream) {
    const float* x        = (const float*)d_in[0];
    const void*  mask     = d_in[1];
    const float* attn_w1  = (const float*)d_in[2];
    const float* attn_b1  = (const float*)d_in[3];
    const float* attn_w2  = (const float*)d_in[4];
    const float* attn_b2  = (const float*)d_in[5];
    const float* gate_w1  = (const float*)d_in[6];
    const float* gate_b1  = (const float*)d_in[7];
    const float* gln_g    = (const float*)d_in[8];
    const float* gln_b    = (const float*)d_in[9];
    const float* gate_w2  = (const float*)d_in[10];
    const float* gate_b2  = (const float*)d_in[11];
    const float* out_w    = (const float*)d_in[12];
    const float* out_b    = (const float*)d_in[13];
    const float* oln_g    = (const float*)d_in[14];
    const float* oln_b    = (const float*)d_in[15];
    float* out = (float*)d_out;

    char* p = (char*)d_ws;
    unsigned char* m8 = (unsigned char*)p;      p += (size_t)BB * NN;          // 128 KB
    unsigned short* w1t = (unsigned short*)p;   p += (size_t)DD * HH * 2;      // 128 KB
    float* attnp = (float*)p;                   p += (size_t)256 * DD * 4;     // 512 KB
    float* sump = (float*)p;                    p += (size_t)256 * DD * 4;
    float* maxp = (float*)p;                    p += (size_t)256 * DD * 4;
    float* bm = (float*)p;                      p += 1024;
    float* bt = (float*)p;                      p += 1024;
    float* bc = (float*)p;                      p += 1024;

    gmsp_prep<<<768, 256, 0, stream>>>(mask, m8, attn_w1, w1t);
    gmsp_fused<<<256, 512, 0, stream>>>(x, w1t, attn_b1, attn_w2, attn_b2, m8,
                                        attnp, sump, maxp, bm, bt, bc);
    gmsp_tail<<<BB, 256, 0, stream>>>(attnp, sump, maxp, bm, bt, bc,
                                      gate_w1, gate_b1, gln_g, gln_b, gate_w2, gate_b2,
                                      out_w, out_b, oln_g, oln_b, out);
}